// Round 6
// baseline (10422.493 us; speedup 1.0000x reference)
//
#include <hip/hip_runtime.h>
#include <stdint.h>
#include <stddef.h>

// Problem dims
#define Mdim 2048
#define Tdim 64
#define INdim 16
#define Hdim 256
#define Gdim 1024
#define NCdim 64
#define OUTdim 192

// Partition: 8 row-groups (rg, 256 rows) x 32 unit-groups (ug, 8 units = 32 gate-dims)
#define S0 276               // padded layer0 W row: 16 z + 256 h + 4 pad
#define S1 516               // padded layer1 W row: 256 h0 + 256 h1 + 4 pad
#define SLICE (32*S0 + 32*S1 + 64)   // 25408 floats per ug-slice (incl 64 biases)
#define RING_SLOTS 16

// ws layout (float offsets)
#define OFF_WP   0
#define OFF_WFCP (OFF_WP + 32 * SLICE)            // [256][64] float4 {g,s,m,0}
#define OFF_H0   (OFF_WFCP + 256 * 64 * 4)        // [2][2048][256]
#define OFF_C0   (OFF_H0 + 2 * Mdim * Hdim)       // [2048][256]
#define OFF_C1   (OFF_C0 + Mdim * Hdim)           // [2048][256]
#define OFF_RING (OFF_C1 + Mdim * Hdim)           // [16][2048][256]
#define WS_TOT   (OFF_RING + RING_SLOTS * Mdim * Hdim)   // ~11.4M floats = 45.5MB

#define HSLAB (Mdim * Hdim)   // 524288

#define ROTL32(v, s) (((v) << (s)) | ((v) >> (32 - (s))))

// JAX threefry2x32
__host__ __device__ inline void tf2x32(uint32_t k0, uint32_t k1, uint32_t x0, uint32_t x1,
                                       uint32_t* o0, uint32_t* o1) {
  uint32_t ks2 = k0 ^ k1 ^ 0x1BD11BDAu;
  x0 += k0; x1 += k1;
  x0 += x1; x1 = ROTL32(x1, 13); x1 ^= x0;
  x0 += x1; x1 = ROTL32(x1, 15); x1 ^= x0;
  x0 += x1; x1 = ROTL32(x1, 26); x1 ^= x0;
  x0 += x1; x1 = ROTL32(x1, 6);  x1 ^= x0;
  x0 += k1; x1 += ks2 + 1u;
  x0 += x1; x1 = ROTL32(x1, 17); x1 ^= x0;
  x0 += x1; x1 = ROTL32(x1, 29); x1 ^= x0;
  x0 += x1; x1 = ROTL32(x1, 16); x1 ^= x0;
  x0 += x1; x1 = ROTL32(x1, 24); x1 ^= x0;
  x0 += ks2; x1 += k0 + 2u;
  x0 += x1; x1 = ROTL32(x1, 13); x1 ^= x0;
  x0 += x1; x1 = ROTL32(x1, 15); x1 ^= x0;
  x0 += x1; x1 = ROTL32(x1, 26); x1 ^= x0;
  x0 += x1; x1 = ROTL32(x1, 6);  x1 ^= x0;
  x0 += k0; x1 += k1 + 3u;
  x0 += x1; x1 = ROTL32(x1, 17); x1 ^= x0;
  x0 += x1; x1 = ROTL32(x1, 29); x1 ^= x0;
  x0 += x1; x1 = ROTL32(x1, 16); x1 ^= x0;
  x0 += x1; x1 = ROTL32(x1, 24); x1 ^= x0;
  x0 += k1; x1 += ks2 + 4u;
  x0 += x1; x1 = ROTL32(x1, 13); x1 ^= x0;
  x0 += x1; x1 = ROTL32(x1, 15); x1 ^= x0;
  x0 += x1; x1 = ROTL32(x1, 26); x1 ^= x0;
  x0 += x1; x1 = ROTL32(x1, 6);  x1 ^= x0;
  x0 += ks2; x1 += k0 + 5u;
  *o0 = x0; *o1 = x1;
}

__device__ inline uint32_t random_bits32(uint32_t ka, uint32_t kb, uint32_t p) {
  uint32_t a, b;
  tf2x32(ka, kb, 0u, p, &a, &b);
  return a ^ b;
}

__device__ inline float bits_to_u01(uint32_t bits) {
  return __uint_as_float((bits >> 9) | 0x3f800000u) - 1.0f;
}

__device__ inline float sigm_fast(float x) { return 1.0f / (1.0f + __expf(-x)); }

__device__ inline float erfinv_f32(float x) {
  float w = -log1pf(-x * x);
  float p;
  if (w < 5.0f) {
    w -= 2.5f;
    p = 2.81022636e-08f;
    p = fmaf(p, w, 3.43273939e-07f);
    p = fmaf(p, w, -3.5233877e-06f);
    p = fmaf(p, w, -4.39150654e-06f);
    p = fmaf(p, w, 0.00021858087f);
    p = fmaf(p, w, -0.00125372503f);
    p = fmaf(p, w, -0.00417768164f);
    p = fmaf(p, w, 0.246640727f);
    p = fmaf(p, w, 1.50140941f);
  } else {
    w = sqrtf(w) - 3.0f;
    p = -0.000200214257f;
    p = fmaf(p, w, 0.000100950558f);
    p = fmaf(p, w, 0.00134934322f);
    p = fmaf(p, w, -0.00367342844f);
    p = fmaf(p, w, 0.00573950773f);
    p = fmaf(p, w, -0.0076224613f);
    p = fmaf(p, w, 0.00943887047f);
    p = fmaf(p, w, 1.00167406f);
    p = fmaf(p, w, 2.83297682f);
  }
  return p * x;
}

__device__ inline void mdn_head(float yg, float ysg, float ym, int lane, uint32_t rid,
                                uint32_t k1a, uint32_t k1b, uint32_t k2a, uint32_t k2b,
                                float* __restrict__ out) {
  uint32_t pp = rid * (uint32_t)NCdim + (uint32_t)lane;
  uint32_t bits = random_bits32(k1a, k1b, pp);
  float u01 = bits_to_u01(bits);
  const float tinyf = 1.17549435e-38f;
  float uu = fmaxf(tinyf, u01 + tinyf);
  float gum = -logf(-logf(uu));
  float val = gum + yg;
  int idx = lane;
#pragma unroll
  for (int s = 1; s < 64; s <<= 1) {
    float ov = __shfl_xor(val, s);
    int oi = __shfl_xor(idx, s);
    if (ov > val || (ov == val && oi < idx)) { val = ov; idx = oi; }
  }
  float mu_sel = __shfl(ym, idx);
  float s_sel = __shfl(ysg, idx);

  uint32_t ebits = random_bits32(k2a, k2b, rid);
  float ue = bits_to_u01(ebits);
  const float lo = __uint_as_float(0xBF7FFFFFu);
  float un = fmaxf(lo, ue * 2.0f + lo);
  float eps = 1.41421356f * erfinv_f32(un);

  float x_pred = mu_sel + expf(s_sel) * eps;

  float mx = yg;
#pragma unroll
  for (int s = 1; s < 64; s <<= 1) mx = fmaxf(mx, __shfl_xor(mx, s));
  float se = expf(yg - mx);
#pragma unroll
  for (int s = 1; s < 64; s <<= 1) se += __shfl_xor(se, s);
  float d = x_pred - ym;
  float lk = -0.5f * d * d - 66.0f * ysg - 58.812066f;
  float ts = expf(yg - mx + lk);
#pragma unroll
  for (int s = 1; s < 64; s <<= 1) ts += __shfl_xor(ts, s);
  float prob = ts / se;

  if (lane == 0) {
    out[rid] = x_pred;
    out[(size_t)Mdim * Tdim + rid] = prob;
  }
}

// Pack per-ug weight slices (padded rows) + biases + FC table.
__global__ void vfpg_prep(const float* __restrict__ Wih0, const float* __restrict__ Whh0,
                          const float* __restrict__ Wih1, const float* __restrict__ Whh1,
                          const float* __restrict__ fcW, const float* __restrict__ bih0,
                          const float* __restrict__ bhh0, const float* __restrict__ bih1,
                          const float* __restrict__ bhh1, float* __restrict__ ws) {
  int i0 = blockIdx.x * blockDim.x + threadIdx.x;
  int n = blockDim.x * gridDim.x;
  const int NWP = 32 * SLICE;
  for (int i = i0; i < NWP; i += n) {
    int ug = i / SLICE, rem = i % SLICE;
    float v = 0.0f;
    if (rem < 32 * S0) {
      int gdi = rem / S0, col = rem % S0;
      int gd = (gdi & 3) * 256 + ug * 8 + (gdi >> 2);
      if (col < 16) v = Wih0[gd * INdim + col];
      else if (col < 272) v = Whh0[gd * Hdim + (col - 16)];
    } else if (rem < 32 * S0 + 32 * S1) {
      int r2 = rem - 32 * S0;
      int gdi = r2 / S1, col = r2 % S1;
      int gd = (gdi & 3) * 256 + ug * 8 + (gdi >> 2);
      if (col < 256) v = Wih1[gd * Hdim + col];
      else if (col < 512) v = Whh1[gd * Hdim + (col - 256)];
    } else {
      int r3 = rem - (32 * S0 + 32 * S1);
      if (r3 < 32) {
        int gd = (r3 & 3) * 256 + ug * 8 + (r3 >> 2);
        v = bih0[gd] + bhh0[gd];
      } else {
        int gdi = r3 - 32;
        int gd = (gdi & 3) * 256 + ug * 8 + (gdi >> 2);
        v = bih1[gd] + bhh1[gd];
      }
    }
    ws[OFF_WP + i] = v;
  }
  float4* wfcp = (float4*)(ws + OFF_WFCP);
  for (int o = i0; o < 256 * 64; o += n) {
    int k = o >> 6, c = o & 63;
    wfcp[o] = make_float4(fcW[c * Hdim + k], fcW[(64 + c) * Hdim + k],
                          fcW[(128 + c) * Hdim + k], 0.0f);
  }
}

// One launch = timestep t of layer0 (h0(t)) + timestep t-1 of layer1 (h1(t-1)).
// Block b: rg = b&7 (rows rg*256..+255), ug = b>>3 (units ug*8..+7).
__launch_bounds__(512, 1)
__global__ void vfpg_step(const float* __restrict__ z, const float* __restrict__ ws,
                          float* __restrict__ h0buf, float* __restrict__ c0w,
                          float* __restrict__ c1w, float* __restrict__ ring, int t) {
  __shared__ __align__(16) float lds[SLICE];   // 101.6 KB weight slice + biases
  __shared__ __align__(16) float gbuf[8192];   // 32 KB gate staging [row256][j8][type4]

  const int tid = threadIdx.x;
  const int rg = blockIdx.x & 7;
  const int ug = blockIdx.x >> 3;
  const bool L0 = (t < Tdim);
  const bool L1 = (t >= 1);

  // cooperative load of this ug's weight slice
  {
    const float4* src = (const float4*)(ws + OFF_WP + (size_t)ug * SLICE);
    float4* dst = (float4*)lds;
    for (int i = tid; i < SLICE / 4; i += 512) dst[i] = src[i];
  }
  __syncthreads();

  const int rgrp = tid >> 5;          // 0..15 (16 rows each)
  const int gdi = tid & 31;           // gate-dim index within slice
  const int mb = rg * 256 + rgrp * 16;
  const int w0b = gdi * S0;
  const int w1b = 32 * S0 + gdi * S1;
  const int bb = 32 * S0 + 32 * S1;

  float acc0[16], acc1[16];
  {
    float b0v = L0 ? lds[bb + gdi] : 0.0f;
    float b1v = L1 ? lds[bb + 32 + gdi] : 0.0f;
#pragma unroll
    for (int r = 0; r < 16; r++) { acc0[r] = b0v; acc1[r] = b1v; }
  }

  // layer0 z-part
  if (L0) {
#pragma unroll
    for (int kz = 0; kz < 4; kz++) {
      float4 w = *(const float4*)&lds[w0b + 4 * kz];
#pragma unroll
      for (int rr = 0; rr < 16; rr++) {
        float4 z4 = *(const float4*)&z[((size_t)(mb + rr) * Tdim + t) * INdim + 4 * kz];
        acc0[rr] = fmaf(z4.x, w.x, acc0[rr]);
        acc0[rr] = fmaf(z4.y, w.y, acc0[rr]);
        acc0[rr] = fmaf(z4.z, w.z, acc0[rr]);
        acc0[rr] = fmaf(z4.w, w.w, acc0[rr]);
      }
    }
  }

  // fused h0(t-1) loop: feeds layer0 (acc0) and layer1 (acc1)
  if (t >= 1) {
    const float* h0p = h0buf + (size_t)((t - 1) & 1) * HSLAB;
#pragma unroll 2
    for (int kh = 0; kh < 64; kh++) {
      float4 w0 = *(const float4*)&lds[w0b + 16 + 4 * kh];
      float4 w1 = *(const float4*)&lds[w1b + 4 * kh];
#pragma unroll
      for (int rr = 0; rr < 16; rr++) {
        float4 h4 = *(const float4*)&h0p[(size_t)(mb + rr) * Hdim + 4 * kh];
        if (L0) {
          acc0[rr] = fmaf(h4.x, w0.x, acc0[rr]);
          acc0[rr] = fmaf(h4.y, w0.y, acc0[rr]);
          acc0[rr] = fmaf(h4.z, w0.z, acc0[rr]);
          acc0[rr] = fmaf(h4.w, w0.w, acc0[rr]);
        }
        acc1[rr] = fmaf(h4.x, w1.x, acc1[rr]);
        acc1[rr] = fmaf(h4.y, w1.y, acc1[rr]);
        acc1[rr] = fmaf(h4.z, w1.z, acc1[rr]);
        acc1[rr] = fmaf(h4.w, w1.w, acc1[rr]);
      }
    }
  }

  // layer1 h1(t-2) part
  if (t >= 2) {
    const float* h1p = ring + (size_t)((t - 2) & (RING_SLOTS - 1)) * HSLAB;
#pragma unroll 2
    for (int kh = 0; kh < 64; kh++) {
      float4 w1 = *(const float4*)&lds[w1b + 256 + 4 * kh];
#pragma unroll
      for (int rr = 0; rr < 16; rr++) {
        float4 h4 = *(const float4*)&h1p[(size_t)(mb + rr) * Hdim + 4 * kh];
        acc1[rr] = fmaf(h4.x, w1.x, acc1[rr]);
        acc1[rr] = fmaf(h4.y, w1.y, acc1[rr]);
        acc1[rr] = fmaf(h4.z, w1.z, acc1[rr]);
        acc1[rr] = fmaf(h4.w, w1.w, acc1[rr]);
      }
    }
  }

  // ---- layer0 cell update ----
  if (L0) {
#pragma unroll
    for (int rr = 0; rr < 16; rr++) gbuf[(rgrp * 16 + rr) * 32 + gdi] = acc0[rr];
  }
  __syncthreads();
  if (L0) {
    const int lr = tid >> 1;
    const int ju = (tid & 1) * 4;
    const int m = rg * 256 + lr;
    const int u0 = ug * 8 + ju;
    float4 cold = make_float4(0.f, 0.f, 0.f, 0.f);
    if (t >= 1) cold = *(const float4*)&c0w[(size_t)m * Hdim + u0];
    float4 cnew, hnew;
#pragma unroll
    for (int i = 0; i < 4; i++) {
      float4 g4 = *(const float4*)&gbuf[lr * 32 + (ju + i) * 4];
      float si = sigm_fast(g4.x);
      float sf = sigm_fast(g4.y);
      float tg = fmaf(2.0f, sigm_fast(2.0f * g4.z), -1.0f);
      float so = sigm_fast(g4.w);
      float cc = sf * (&cold.x)[i] + si * tg;
      (&cnew.x)[i] = cc;
      (&hnew.x)[i] = so * fmaf(2.0f, sigm_fast(2.0f * cc), -1.0f);
    }
    *(float4*)&c0w[(size_t)m * Hdim + u0] = cnew;
    *(float4*)&h0buf[(size_t)(t & 1) * HSLAB + (size_t)m * Hdim + u0] = hnew;
  }
  __syncthreads();

  // ---- layer1 cell update (h1(t-1)) ----
  if (L1) {
#pragma unroll
    for (int rr = 0; rr < 16; rr++) gbuf[(rgrp * 16 + rr) * 32 + gdi] = acc1[rr];
  }
  __syncthreads();
  if (L1) {
    const int lr = tid >> 1;
    const int ju = (tid & 1) * 4;
    const int m = rg * 256 + lr;
    const int u0 = ug * 8 + ju;
    float4 cold = make_float4(0.f, 0.f, 0.f, 0.f);
    if (t >= 2) cold = *(const float4*)&c1w[(size_t)m * Hdim + u0];
    float4 cnew, hnew;
#pragma unroll
    for (int i = 0; i < 4; i++) {
      float4 g4 = *(const float4*)&gbuf[lr * 32 + (ju + i) * 4];
      float si = sigm_fast(g4.x);
      float sf = sigm_fast(g4.y);
      float tg = fmaf(2.0f, sigm_fast(2.0f * g4.z), -1.0f);
      float so = sigm_fast(g4.w);
      float cc = sf * (&cold.x)[i] + si * tg;
      (&cnew.x)[i] = cc;
      (&hnew.x)[i] = so * fmaf(2.0f, sigm_fast(2.0f * cc), -1.0f);
    }
    *(float4*)&c1w[(size_t)m * Hdim + u0] = cnew;
    *(float4*)&ring[(size_t)((t - 1) & (RING_SLOTS - 1)) * HSLAB + (size_t)m * Hdim + u0] = hnew;
  }
}

// Batched FC + MDN head: covers 16 timesteps (ring slots) x 2048 rows.
__launch_bounds__(512, 1)
__global__ void vfpg_head(const float* __restrict__ ws, const float* __restrict__ ring,
                          const float* __restrict__ fcb, float* __restrict__ out, int tbase,
                          uint32_t k1a, uint32_t k1b, uint32_t k2a, uint32_t k2b) {
  __shared__ __align__(16) float hs[8][Hdim];
  const int lane = threadIdx.x & 63;
  const int wid = threadIdx.x >> 6;
  const int rid = blockIdx.x * 8 + wid;        // 0..32767
  const int slot = rid >> 11;                  // 0..15
  const int m = rid & 2047;
  const int t = tbase + slot;

  const float4* WFCP = (const float4*)(ws + OFF_WFCP);
  const float* hrow = ring + (size_t)slot * HSLAB + (size_t)m * Hdim;

  float4 hv = *(const float4*)&hrow[4 * lane];
  *(float4*)&hs[wid][4 * lane] = hv;
  __builtin_amdgcn_s_waitcnt(0);
  float yg = fcb[lane], ysg = fcb[64 + lane], ym = fcb[128 + lane];
#pragma unroll 2
  for (int k4 = 0; k4 < 64; k4++) {
    float4 h4 = *(const float4*)&hs[wid][4 * k4];
#pragma unroll
    for (int j = 0; j < 4; j++) {
      float4 w = WFCP[(4 * k4 + j) * 64 + lane];
      float hh = (&h4.x)[j];
      yg = fmaf(hh, w.x, yg);
      ysg = fmaf(hh, w.y, ysg);
      ym = fmaf(hh, w.z, ym);
    }
  }
  uint32_t rid_out = (uint32_t)m * Tdim + (uint32_t)t;
  mdn_head(yg, ysg, ym, lane, rid_out, k1a, k1b, k2a, k2b, out);
}

extern "C" void kernel_launch(void* const* d_in, const int* in_sizes, int n_in,
                              void* d_out, int out_size, void* d_ws, size_t ws_size,
                              hipStream_t stream) {
  const float* z    = (const float*)d_in[0];
  const float* Wih0 = (const float*)d_in[1];
  const float* Whh0 = (const float*)d_in[2];
  const float* bih0 = (const float*)d_in[3];
  const float* bhh0 = (const float*)d_in[4];
  const float* Wih1 = (const float*)d_in[5];
  const float* Whh1 = (const float*)d_in[6];
  const float* bih1 = (const float*)d_in[7];
  const float* bhh1 = (const float*)d_in[8];
  const float* fcW  = (const float*)d_in[9];
  const float* fcb  = (const float*)d_in[10];
  float* ws = (float*)d_ws;
  float* out = (float*)d_out;

  if (ws_size < (size_t)WS_TOT * sizeof(float)) return;  // needs ~45.5 MB (<137.7 proven)

  vfpg_prep<<<dim3(512), dim3(256), 0, stream>>>(
      Wih0, Whh0, Wih1, Whh1, fcW, bih0, bhh0, bih1, bhh1, ws);

  uint32_t k1a, k1b, k2a, k2b;
  tf2x32(0u, 42u, 0u, 0u, &k1a, &k1b);
  tf2x32(0u, 42u, 0u, 1u, &k2a, &k2b);

  float* h0buf = ws + OFF_H0;
  float* c0w = ws + OFF_C0;
  float* c1w = ws + OFF_C1;
  float* ring = ws + OFF_RING;

  for (int t = 0; t <= Tdim; t++) {
    vfpg_step<<<dim3(256), dim3(512), 0, stream>>>(z, ws, h0buf, c0w, c1w, ring, t);
    if (t == 16 || t == 32 || t == 48) {
      vfpg_head<<<dim3(4096), dim3(512), 0, stream>>>(ws, ring, fcb, out, t - 16,
                                                      k1a, k1b, k2a, k2b);
    }
  }
  vfpg_head<<<dim3(4096), dim3(512), 0, stream>>>(ws, ring, fcb, out, 48,
                                                  k1a, k1b, k2a, k2b);
}

// Round 7
// 4474.146 us; speedup vs baseline: 2.3295x; 2.3295x over previous
//
#include <hip/hip_runtime.h>
#include <stdint.h>
#include <stddef.h>

// Problem dims
#define Mdim 2048
#define Tdim 64
#define INdim 16
#define Hdim 256
#define NCdim 64

// Partition: 8 rg (256 rows) x 64 ug (4 units = 16 gates, interleaved g=ul*4+ty)
#define S0P 276                       // padded W0 row: 16 z + 256 h0 + 4 pad
#define S1P 516                       // padded W1 row: 256 h0 + 256 h1 + 4 pad
#define SL_W (16*S0P + 16*S1P)        // 12672 floats
#define SLICE (SL_W + 32)             // +16 b0 +16 b1 = 12704
#define NUG 64
#define HSLAB (256 * 2048)            // 524288
#define RSLOTS 16

// ws layout (float offsets)
#define OFF_WP    0
#define OFF_WFCP  (OFF_WP + NUG * SLICE)        // [256 k][64 c] float4 {g,s,m,0}
#define OFF_H0    (OFF_WFCP + 256 * 64 * 4)     // [2][256 u][2048 m]
#define OFF_C0    (OFF_H0 + 2 * HSLAB)          // [256 u][2048 m]
#define OFF_C1    (OFF_C0 + HSLAB)
#define OFF_RING  (OFF_C1 + HSLAB)              // [16][256 u][2048 m]
#define OFF_RING2 (OFF_RING + RSLOTS * HSLAB)   // [16][2048 m][256 u]
#define WS_TOT    (OFF_RING2 + RSLOTS * HSLAB)  // 19,752,960 fl = 79 MB

#define ROTL32(v, s) (((v) << (s)) | ((v) >> (32 - (s))))

// JAX threefry2x32
__host__ __device__ inline void tf2x32(uint32_t k0, uint32_t k1, uint32_t x0, uint32_t x1,
                                       uint32_t* o0, uint32_t* o1) {
  uint32_t ks2 = k0 ^ k1 ^ 0x1BD11BDAu;
  x0 += k0; x1 += k1;
  x0 += x1; x1 = ROTL32(x1, 13); x1 ^= x0;
  x0 += x1; x1 = ROTL32(x1, 15); x1 ^= x0;
  x0 += x1; x1 = ROTL32(x1, 26); x1 ^= x0;
  x0 += x1; x1 = ROTL32(x1, 6);  x1 ^= x0;
  x0 += k1; x1 += ks2 + 1u;
  x0 += x1; x1 = ROTL32(x1, 17); x1 ^= x0;
  x0 += x1; x1 = ROTL32(x1, 29); x1 ^= x0;
  x0 += x1; x1 = ROTL32(x1, 16); x1 ^= x0;
  x0 += x1; x1 = ROTL32(x1, 24); x1 ^= x0;
  x0 += ks2; x1 += k0 + 2u;
  x0 += x1; x1 = ROTL32(x1, 13); x1 ^= x0;
  x0 += x1; x1 = ROTL32(x1, 15); x1 ^= x0;
  x0 += x1; x1 = ROTL32(x1, 26); x1 ^= x0;
  x0 += x1; x1 = ROTL32(x1, 6);  x1 ^= x0;
  x0 += k0; x1 += k1 + 3u;
  x0 += x1; x1 = ROTL32(x1, 17); x1 ^= x0;
  x0 += x1; x1 = ROTL32(x1, 29); x1 ^= x0;
  x0 += x1; x1 = ROTL32(x1, 16); x1 ^= x0;
  x0 += x1; x1 = ROTL32(x1, 24); x1 ^= x0;
  x0 += k1; x1 += ks2 + 4u;
  x0 += x1; x1 = ROTL32(x1, 13); x1 ^= x0;
  x0 += x1; x1 = ROTL32(x1, 15); x1 ^= x0;
  x0 += x1; x1 = ROTL32(x1, 26); x1 ^= x0;
  x0 += x1; x1 = ROTL32(x1, 6);  x1 ^= x0;
  x0 += ks2; x1 += k0 + 5u;
  *o0 = x0; *o1 = x1;
}

__device__ inline uint32_t random_bits32(uint32_t ka, uint32_t kb, uint32_t p) {
  uint32_t a, b;
  tf2x32(ka, kb, 0u, p, &a, &b);
  return a ^ b;
}

__device__ inline float bits_to_u01(uint32_t bits) {
  return __uint_as_float((bits >> 9) | 0x3f800000u) - 1.0f;
}

__device__ inline float sigm_fast(float x) { return 1.0f / (1.0f + __expf(-x)); }

__device__ inline float erfinv_f32(float x) {
  float w = -log1pf(-x * x);
  float p;
  if (w < 5.0f) {
    w -= 2.5f;
    p = 2.81022636e-08f;
    p = fmaf(p, w, 3.43273939e-07f);
    p = fmaf(p, w, -3.5233877e-06f);
    p = fmaf(p, w, -4.39150654e-06f);
    p = fmaf(p, w, 0.00021858087f);
    p = fmaf(p, w, -0.00125372503f);
    p = fmaf(p, w, -0.00417768164f);
    p = fmaf(p, w, 0.246640727f);
    p = fmaf(p, w, 1.50140941f);
  } else {
    w = sqrtf(w) - 3.0f;
    p = -0.000200214257f;
    p = fmaf(p, w, 0.000100950558f);
    p = fmaf(p, w, 0.00134934322f);
    p = fmaf(p, w, -0.00367342844f);
    p = fmaf(p, w, 0.00573950773f);
    p = fmaf(p, w, -0.0076224613f);
    p = fmaf(p, w, 0.00943887047f);
    p = fmaf(p, w, 1.00167406f);
    p = fmaf(p, w, 2.83297682f);
  }
  return p * x;
}

__device__ inline void mdn_head(float yg, float ysg, float ym, int lane, uint32_t rid,
                                uint32_t k1a, uint32_t k1b, uint32_t k2a, uint32_t k2b,
                                float* __restrict__ out) {
  uint32_t pp = rid * (uint32_t)NCdim + (uint32_t)lane;
  uint32_t bits = random_bits32(k1a, k1b, pp);
  float u01 = bits_to_u01(bits);
  const float tinyf = 1.17549435e-38f;
  float uu = fmaxf(tinyf, u01 + tinyf);
  float gum = -logf(-logf(uu));
  float val = gum + yg;
  int idx = lane;
#pragma unroll
  for (int s = 1; s < 64; s <<= 1) {
    float ov = __shfl_xor(val, s);
    int oi = __shfl_xor(idx, s);
    if (ov > val || (ov == val && oi < idx)) { val = ov; idx = oi; }
  }
  float mu_sel = __shfl(ym, idx);
  float s_sel = __shfl(ysg, idx);

  uint32_t ebits = random_bits32(k2a, k2b, rid);
  float ue = bits_to_u01(ebits);
  const float lo = __uint_as_float(0xBF7FFFFFu);
  float un2 = fmaxf(lo, ue * 2.0f + lo);
  float eps = 1.41421356f * erfinv_f32(un2);

  float x_pred = mu_sel + expf(s_sel) * eps;

  float mx = yg;
#pragma unroll
  for (int s = 1; s < 64; s <<= 1) mx = fmaxf(mx, __shfl_xor(mx, s));
  float se = expf(yg - mx);
#pragma unroll
  for (int s = 1; s < 64; s <<= 1) se += __shfl_xor(se, s);
  float d = x_pred - ym;
  float lk = -0.5f * d * d - 66.0f * ysg - 58.812066f;
  float ts = expf(yg - mx + lk);
#pragma unroll
  for (int s = 1; s < 64; s <<= 1) ts += __shfl_xor(ts, s);
  float prob = ts / se;

  if (lane == 0) {
    out[rid] = x_pred;
    out[(size_t)Mdim * Tdim + rid] = prob;
  }
}

// Pack per-ug weight slices (padded rows, gate-interleaved) + FC table.
__global__ void vfpg_prep(const float* __restrict__ Wih0, const float* __restrict__ Whh0,
                          const float* __restrict__ Wih1, const float* __restrict__ Whh1,
                          const float* __restrict__ fcW, const float* __restrict__ bih0,
                          const float* __restrict__ bhh0, const float* __restrict__ bih1,
                          const float* __restrict__ bhh1, float* __restrict__ ws) {
  int i0 = blockIdx.x * blockDim.x + threadIdx.x;
  int n = blockDim.x * gridDim.x;
  const int NWP = NUG * SLICE;
  for (int i = i0; i < NWP; i += n) {
    int ug = i / SLICE, r = i % SLICE;
    float v = 0.0f;
    if (r < 16 * S0P) {
      int gdi = r / S0P, col = r % S0P;
      int gd = (gdi & 3) * 256 + ug * 4 + (gdi >> 2);
      if (col < 16) v = Wih0[gd * INdim + col];
      else if (col < 272) v = Whh0[gd * Hdim + (col - 16)];
    } else if (r < SL_W) {
      int r2 = r - 16 * S0P;
      int gdi = r2 / S1P, col = r2 % S1P;
      int gd = (gdi & 3) * 256 + ug * 4 + (gdi >> 2);
      if (col < 256) v = Wih1[gd * Hdim + col];
      else if (col < 512) v = Whh1[gd * Hdim + (col - 256)];
    } else {
      int r3 = r - SL_W;
      int gdi = (r3 & 15);
      int gd = (gdi & 3) * 256 + ug * 4 + (gdi >> 2);
      v = (r3 < 16) ? (bih0[gd] + bhh0[gd]) : (bih1[gd] + bhh1[gd]);
    }
    ws[OFF_WP + i] = v;
  }
  float4* wfcp = (float4*)(ws + OFF_WFCP);
  for (int o = i0; o < 256 * 64; o += n) {
    int k = o >> 6, c = o & 63;
    wfcp[o] = make_float4(fcW[c * Hdim + k], fcW[(64 + c) * Hdim + k],
                          fcW[(128 + c) * Hdim + k], 0.0f);
  }
}

// Launch t: layer0 step t (h0(t)) + layer1 step t-1 (h1(t-1)).
// MODE 0: t=0 (L0 only); 1: 1..63 (both); 2: t=64 (L1 only).
template <int MODE>
__launch_bounds__(512, 4)
__global__ void vfpg_step(const float* __restrict__ z, const float* __restrict__ ws,
                          float* __restrict__ h0buf, float* __restrict__ c0w,
                          float* __restrict__ c1w, float* __restrict__ ring,
                          float* __restrict__ ring2, int t) {
  constexpr bool DO_L0 = (MODE <= 1);
  constexpr bool DO_L1 = (MODE >= 1);
  __shared__ __align__(16) float lw[SL_W];   // 50.7 KB weights
  __shared__ __align__(16) float lb[32];
  __shared__ __align__(16) float un[4096];   // 16 KB: z-tile / h dbuf / gate buf

  const int tid = threadIdx.x;
  const int rg = blockIdx.x & 7;             // rg r -> XCD r (all 64 ug-blocks co-located)
  const int ug = blockIdx.x >> 3;
  const int mb = rg * 256;

  {
    const float4* src = (const float4*)(ws + OFF_WP + (size_t)ug * SLICE);
    for (int i = tid; i < SLICE / 4; i += 512) {
      float4 v = src[i];
      if (i < SL_W / 4) ((float4*)lw)[i] = v;
      else ((float4*)lb)[i - SL_W / 4] = v;
    }
  }
  __syncthreads();

  const int r16 = tid >> 4;        // 32 row-groups of 8 rows
  const int gdi = tid & 15;        // gate within slice (ul*4+ty)
  const int ustg = tid >> 6;       // staging: 8 k-rows
  const int m4 = (tid & 63) * 4;   // staging: 64 float4 per k-row

  float a0[8], a1[8];
  {
    float b0v = lb[gdi], b1v = lb[16 + gdi];
#pragma unroll
    for (int r = 0; r < 8; r++) { a0[r] = b0v; a1[r] = b1v; }
  }

  // ---- Z phase (K=16) ----
  if (DO_L0) {
#pragma unroll
    for (int rep = 0; rep < 2; rep++) {
      int it = tid + rep * 512;
      int row = it & 255, f4 = it >> 8;
      float4 zz = *(const float4*)&z[(size_t)(mb + row) * 1024 + t * 16 + f4 * 4];
      *(float4*)&un[row * 16 + f4 * 4] = zz;
    }
    __syncthreads();
#pragma unroll
    for (int f4 = 0; f4 < 4; f4++) {
      float4 w = *(const float4*)&lw[gdi * S0P + f4 * 4];
#pragma unroll
      for (int rr = 0; rr < 8; rr++) {
        float4 q = *(const float4*)&un[(r16 * 8 + rr) * 16 + f4 * 4];
        a0[rr] = fmaf(q.x, w.x, a0[rr]);
        a0[rr] = fmaf(q.y, w.y, a0[rr]);
        a0[rr] = fmaf(q.z, w.z, a0[rr]);
        a0[rr] = fmaf(q.w, w.w, a0[rr]);
      }
    }
    __syncthreads();
  }

  // ---- H0 phase: h0(t-1), 32 chunks of 8k, dbuf, feeds a0 (and a1 if L1) ----
  if (MODE >= 1) {
    const float* h0p = h0buf + (size_t)((t - 1) & 1) * HSLAB + mb;
    float4 stg = *(const float4*)&h0p[(size_t)ustg * 2048 + m4];
#pragma unroll 1
    for (int kk = 0; kk < 32; kk++) {
      float* buf = un + (kk & 1) * 2048;
      float4 nst = stg;
      if (kk < 31) nst = *(const float4*)&h0p[(size_t)(kk * 8 + 8 + ustg) * 2048 + m4];
      *(float4*)&buf[ustg * 256 + m4] = stg;
      __syncthreads();
      float w0v[8], w1v[8];
      if (DO_L0) {
        float4 wa = *(const float4*)&lw[gdi * S0P + 16 + kk * 8];
        float4 wb = *(const float4*)&lw[gdi * S0P + 16 + kk * 8 + 4];
        w0v[0] = wa.x; w0v[1] = wa.y; w0v[2] = wa.z; w0v[3] = wa.w;
        w0v[4] = wb.x; w0v[5] = wb.y; w0v[6] = wb.z; w0v[7] = wb.w;
      }
      if (DO_L1) {
        float4 wa = *(const float4*)&lw[16 * S0P + gdi * S1P + kk * 8];
        float4 wb = *(const float4*)&lw[16 * S0P + gdi * S1P + kk * 8 + 4];
        w1v[0] = wa.x; w1v[1] = wa.y; w1v[2] = wa.z; w1v[3] = wa.w;
        w1v[4] = wb.x; w1v[5] = wb.y; w1v[6] = wb.z; w1v[7] = wb.w;
      }
#pragma unroll
      for (int k = 0; k < 8; k++) {
        float4 hA = *(const float4*)&buf[k * 256 + r16 * 8];
        float4 hB = *(const float4*)&buf[k * 256 + r16 * 8 + 4];
        if (DO_L0) {
          a0[0] = fmaf(hA.x, w0v[k], a0[0]); a0[1] = fmaf(hA.y, w0v[k], a0[1]);
          a0[2] = fmaf(hA.z, w0v[k], a0[2]); a0[3] = fmaf(hA.w, w0v[k], a0[3]);
          a0[4] = fmaf(hB.x, w0v[k], a0[4]); a0[5] = fmaf(hB.y, w0v[k], a0[5]);
          a0[6] = fmaf(hB.z, w0v[k], a0[6]); a0[7] = fmaf(hB.w, w0v[k], a0[7]);
        }
        if (DO_L1) {
          a1[0] = fmaf(hA.x, w1v[k], a1[0]); a1[1] = fmaf(hA.y, w1v[k], a1[1]);
          a1[2] = fmaf(hA.z, w1v[k], a1[2]); a1[3] = fmaf(hA.w, w1v[k], a1[3]);
          a1[4] = fmaf(hB.x, w1v[k], a1[4]); a1[5] = fmaf(hB.y, w1v[k], a1[5]);
          a1[6] = fmaf(hB.z, w1v[k], a1[6]); a1[7] = fmaf(hB.w, w1v[k], a1[7]);
        }
      }
      stg = nst;
    }
  }

  // ---- H1 phase: h1(t-2), 32 chunks, feeds a1 ----
  if (DO_L1 && t >= 2) {
    const float* h1p = ring + (size_t)((t - 2) & 15) * HSLAB + mb;
    float4 stg = *(const float4*)&h1p[(size_t)ustg * 2048 + m4];
    __syncthreads();   // drain H0 compute before overwriting un
#pragma unroll 1
    for (int kk = 0; kk < 32; kk++) {
      float* buf = un + (kk & 1) * 2048;
      float4 nst = stg;
      if (kk < 31) nst = *(const float4*)&h1p[(size_t)(kk * 8 + 8 + ustg) * 2048 + m4];
      *(float4*)&buf[ustg * 256 + m4] = stg;
      __syncthreads();
      float4 wa = *(const float4*)&lw[16 * S0P + gdi * S1P + 256 + kk * 8];
      float4 wb = *(const float4*)&lw[16 * S0P + gdi * S1P + 256 + kk * 8 + 4];
      float w1v[8] = {wa.x, wa.y, wa.z, wa.w, wb.x, wb.y, wb.z, wb.w};
#pragma unroll
      for (int k = 0; k < 8; k++) {
        float4 hA = *(const float4*)&buf[k * 256 + r16 * 8];
        float4 hB = *(const float4*)&buf[k * 256 + r16 * 8 + 4];
        a1[0] = fmaf(hA.x, w1v[k], a1[0]); a1[1] = fmaf(hA.y, w1v[k], a1[1]);
        a1[2] = fmaf(hA.z, w1v[k], a1[2]); a1[3] = fmaf(hA.w, w1v[k], a1[3]);
        a1[4] = fmaf(hB.x, w1v[k], a1[4]); a1[5] = fmaf(hB.y, w1v[k], a1[5]);
        a1[6] = fmaf(hB.z, w1v[k], a1[6]); a1[7] = fmaf(hB.w, w1v[k], a1[7]);
      }
      stg = nst;
    }
  }

  // ---- L0 cell update ----
  if (DO_L0) {
    __syncthreads();
#pragma unroll
    for (int rr = 0; rr < 8; rr++) un[(r16 * 8 + rr) * 16 + gdi] = a0[rr];
    __syncthreads();
    float* h0cur = h0buf + (size_t)(t & 1) * HSLAB;
#pragma unroll
    for (int rep = 0; rep < 2; rep++) {
      int it = tid + rep * 512;
      int ul = it >> 8, row = it & 255;
      float4 q = *(const float4*)&un[row * 16 + ul * 4];
      int u = ug * 4 + ul;
      size_t idx = (size_t)u * 2048 + mb + row;
      float cold = (MODE == 1) ? c0w[idx] : 0.0f;
      float si = sigm_fast(q.x), sf = sigm_fast(q.y);
      float tg = fmaf(2.0f, sigm_fast(2.0f * q.z), -1.0f);
      float so = sigm_fast(q.w);
      float cc = fmaf(sf, cold, si * tg);
      c0w[idx] = cc;
      h0cur[idx] = so * fmaf(2.0f, sigm_fast(2.0f * cc), -1.0f);
    }
  }

  // ---- L1 cell update (h1(t-1)) ----
  if (DO_L1) {
    __syncthreads();
#pragma unroll
    for (int rr = 0; rr < 8; rr++) un[(r16 * 8 + rr) * 16 + gdi] = a1[rr];
    __syncthreads();
    int slot = (t - 1) & 15;
    float* r1 = ring + (size_t)slot * HSLAB;
    float* r2 = ring2 + (size_t)slot * HSLAB;
#pragma unroll
    for (int rep = 0; rep < 2; rep++) {
      int it = tid + rep * 512;
      int ul = it >> 8, row = it & 255;
      float4 q = *(const float4*)&un[row * 16 + ul * 4];
      int u = ug * 4 + ul;
      size_t idx = (size_t)u * 2048 + mb + row;
      float cold = (t >= 2) ? c1w[idx] : 0.0f;
      float si = sigm_fast(q.x), sf = sigm_fast(q.y);
      float tg = fmaf(2.0f, sigm_fast(2.0f * q.z), -1.0f);
      float so = sigm_fast(q.w);
      float cc = fmaf(sf, cold, si * tg);
      c1w[idx] = cc;
      float hh = so * fmaf(2.0f, sigm_fast(2.0f * cc), -1.0f);
      r1[idx] = hh;
      r2[(size_t)(mb + row) * 256 + u] = hh;
    }
  }
}

// Head: FC + MDN for 16 slots x 2048 rows; wave = 4 rows (w-loads shared).
__launch_bounds__(512, 4)
__global__ void vfpg_head(const float* __restrict__ ws, const float* __restrict__ fcb,
                          float* __restrict__ out, int tbase,
                          uint32_t k1a, uint32_t k1b, uint32_t k2a, uint32_t k2b) {
  __shared__ __align__(16) float hsw[8][4][Hdim];   // 32 KB
  const int tid = threadIdx.x;
  const int lane = tid & 63, wid = tid >> 6;
  const int rb4 = blockIdx.x * 8 + wid;      // 0..8191 (4-row groups)
  const int slot = rb4 >> 9;                 // 0..15
  const int mbase = (rb4 << 2) & 2047;

  const float* r2 = ws + OFF_RING2 + (size_t)slot * HSLAB + (size_t)mbase * 256;
  const float4* WFCP = (const float4*)(ws + OFF_WFCP);

#pragma unroll
  for (int rr = 0; rr < 4; rr++)
    *(float4*)&hsw[wid][rr][lane * 4] = *(const float4*)&r2[rr * 256 + lane * 4];
  __builtin_amdgcn_s_waitcnt(0);

  float yg[4], ys[4], ym[4];
#pragma unroll
  for (int rr = 0; rr < 4; rr++) {
    yg[rr] = fcb[lane]; ys[rr] = fcb[64 + lane]; ym[rr] = fcb[128 + lane];
  }
#pragma unroll 2
  for (int k4 = 0; k4 < 64; k4++) {
    float4 h4[4];
#pragma unroll
    for (int rr = 0; rr < 4; rr++) h4[rr] = *(const float4*)&hsw[wid][rr][k4 * 4];
#pragma unroll
    for (int j = 0; j < 4; j++) {
      float4 w = WFCP[(k4 * 4 + j) * 64 + lane];
#pragma unroll
      for (int rr = 0; rr < 4; rr++) {
        float hv = (&h4[rr].x)[j];
        yg[rr] = fmaf(hv, w.x, yg[rr]);
        ys[rr] = fmaf(hv, w.y, ys[rr]);
        ym[rr] = fmaf(hv, w.z, ym[rr]);
      }
    }
  }
  int tt = tbase + slot;
#pragma unroll 1
  for (int rr = 0; rr < 4; rr++) {
    uint32_t rid = (uint32_t)(mbase + rr) * Tdim + (uint32_t)tt;
    mdn_head(yg[rr], ys[rr], ym[rr], lane, rid, k1a, k1b, k2a, k2b, out);
  }
}

extern "C" void kernel_launch(void* const* d_in, const int* in_sizes, int n_in,
                              void* d_out, int out_size, void* d_ws, size_t ws_size,
                              hipStream_t stream) {
  const float* z    = (const float*)d_in[0];
  const float* Wih0 = (const float*)d_in[1];
  const float* Whh0 = (const float*)d_in[2];
  const float* bih0 = (const float*)d_in[3];
  const float* bhh0 = (const float*)d_in[4];
  const float* Wih1 = (const float*)d_in[5];
  const float* Whh1 = (const float*)d_in[6];
  const float* bih1 = (const float*)d_in[7];
  const float* bhh1 = (const float*)d_in[8];
  const float* fcW  = (const float*)d_in[9];
  const float* fcb  = (const float*)d_in[10];
  float* ws = (float*)d_ws;
  float* out = (float*)d_out;

  if (ws_size < (size_t)WS_TOT * sizeof(float)) return;  // ~79 MB (<137.7 proven)

  vfpg_prep<<<dim3(512), dim3(256), 0, stream>>>(
      Wih0, Whh0, Wih1, Whh1, fcW, bih0, bhh0, bih1, bhh1, ws);

  uint32_t k1a, k1b, k2a, k2b;
  tf2x32(0u, 42u, 0u, 0u, &k1a, &k1b);
  tf2x32(0u, 42u, 0u, 1u, &k2a, &k2b);

  float* h0buf = ws + OFF_H0;
  float* c0w = ws + OFF_C0;
  float* c1w = ws + OFF_C1;
  float* ring = ws + OFF_RING;
  float* ring2 = ws + OFF_RING2;

  vfpg_step<0><<<dim3(512), dim3(512), 0, stream>>>(z, ws, h0buf, c0w, c1w, ring, ring2, 0);
  for (int t = 1; t <= 63; t++) {
    vfpg_step<1><<<dim3(512), dim3(512), 0, stream>>>(z, ws, h0buf, c0w, c1w, ring, ring2, t);
    if (t == 16 || t == 32 || t == 48) {
      vfpg_head<<<dim3(1024), dim3(512), 0, stream>>>(ws, fcb, out, t - 16,
                                                      k1a, k1b, k2a, k2b);
    }
  }
  vfpg_step<2><<<dim3(512), dim3(512), 0, stream>>>(z, ws, h0buf, c0w, c1w, ring, ring2, 64);
  vfpg_head<<<dim3(1024), dim3(512), 0, stream>>>(ws, fcb, out, 48, k1a, k1b, k2a, k2b);
}

// Round 8
// 4055.054 us; speedup vs baseline: 2.5702x; 1.1034x over previous
//
#include <hip/hip_runtime.h>
#include <stdint.h>
#include <stddef.h>

// Problem dims
#define Mdim 2048
#define Tdim 64
#define INdim 16
#define Hdim 256
#define NCdim 64

// Partition: 8 rg (256 rows) x 64 ug (4 units = 16 gates, interleaved g=ul*4+ty)
#define S0P 276                       // padded W0 row: 16 z + 256 h0 + 4 pad
#define S1P 516                       // padded W1 row: 256 h0 + 256 h1 + 4 pad
#define SL_W (16*S0P + 16*S1P)        // 12672 floats
#define SLICE (SL_W + 32)             // +16 b0 +16 b1 = 12704
#define NUG 64
#define HSLAB (256 * 2048)            // 524288
#define RSLOTS 16
#define W1OFF (16 * S0P)

// ws layout (float offsets) — identical to R7
#define OFF_WP    0
#define OFF_WFCP  (OFF_WP + NUG * SLICE)        // [256 k][64 c] float4 {g,s,m,0}
#define OFF_H0    (OFF_WFCP + 256 * 64 * 4)     // [2][256 u][2048 m]
#define OFF_C0    (OFF_H0 + 2 * HSLAB)          // [256 u][2048 m]
#define OFF_C1    (OFF_C0 + HSLAB)
#define OFF_RING  (OFF_C1 + HSLAB)              // [16][256 u][2048 m]
#define OFF_RING2 (OFF_RING + RSLOTS * HSLAB)   // [16][2048 m][256 u]
#define WS_TOT    (OFF_RING2 + RSLOTS * HSLAB)  // ~79 MB

#define ROTL32(v, s) (((v) << (s)) | ((v) >> (32 - (s))))

// JAX threefry2x32
__host__ __device__ inline void tf2x32(uint32_t k0, uint32_t k1, uint32_t x0, uint32_t x1,
                                       uint32_t* o0, uint32_t* o1) {
  uint32_t ks2 = k0 ^ k1 ^ 0x1BD11BDAu;
  x0 += k0; x1 += k1;
  x0 += x1; x1 = ROTL32(x1, 13); x1 ^= x0;
  x0 += x1; x1 = ROTL32(x1, 15); x1 ^= x0;
  x0 += x1; x1 = ROTL32(x1, 26); x1 ^= x0;
  x0 += x1; x1 = ROTL32(x1, 6);  x1 ^= x0;
  x0 += k1; x1 += ks2 + 1u;
  x0 += x1; x1 = ROTL32(x1, 17); x1 ^= x0;
  x0 += x1; x1 = ROTL32(x1, 29); x1 ^= x0;
  x0 += x1; x1 = ROTL32(x1, 16); x1 ^= x0;
  x0 += x1; x1 = ROTL32(x1, 24); x1 ^= x0;
  x0 += ks2; x1 += k0 + 2u;
  x0 += x1; x1 = ROTL32(x1, 13); x1 ^= x0;
  x0 += x1; x1 = ROTL32(x1, 15); x1 ^= x0;
  x0 += x1; x1 = ROTL32(x1, 26); x1 ^= x0;
  x0 += x1; x1 = ROTL32(x1, 6);  x1 ^= x0;
  x0 += k0; x1 += k1 + 3u;
  x0 += x1; x1 = ROTL32(x1, 17); x1 ^= x0;
  x0 += x1; x1 = ROTL32(x1, 29); x1 ^= x0;
  x0 += x1; x1 = ROTL32(x1, 16); x1 ^= x0;
  x0 += x1; x1 = ROTL32(x1, 24); x1 ^= x0;
  x0 += k1; x1 += ks2 + 4u;
  x0 += x1; x1 = ROTL32(x1, 13); x1 ^= x0;
  x0 += x1; x1 = ROTL32(x1, 15); x1 ^= x0;
  x0 += x1; x1 = ROTL32(x1, 26); x1 ^= x0;
  x0 += x1; x1 = ROTL32(x1, 6);  x1 ^= x0;
  x0 += ks2; x1 += k0 + 5u;
  *o0 = x0; *o1 = x1;
}

__device__ inline uint32_t random_bits32(uint32_t ka, uint32_t kb, uint32_t p) {
  uint32_t a, b;
  tf2x32(ka, kb, 0u, p, &a, &b);
  return a ^ b;
}

__device__ inline float bits_to_u01(uint32_t bits) {
  return __uint_as_float((bits >> 9) | 0x3f800000u) - 1.0f;
}

__device__ inline float sigm_fast(float x) { return 1.0f / (1.0f + __expf(-x)); }

__device__ inline float erfinv_f32(float x) {
  float w = -log1pf(-x * x);
  float p;
  if (w < 5.0f) {
    w -= 2.5f;
    p = 2.81022636e-08f;
    p = fmaf(p, w, 3.43273939e-07f);
    p = fmaf(p, w, -3.5233877e-06f);
    p = fmaf(p, w, -4.39150654e-06f);
    p = fmaf(p, w, 0.00021858087f);
    p = fmaf(p, w, -0.00125372503f);
    p = fmaf(p, w, -0.00417768164f);
    p = fmaf(p, w, 0.246640727f);
    p = fmaf(p, w, 1.50140941f);
  } else {
    w = sqrtf(w) - 3.0f;
    p = -0.000200214257f;
    p = fmaf(p, w, 0.000100950558f);
    p = fmaf(p, w, 0.00134934322f);
    p = fmaf(p, w, -0.00367342844f);
    p = fmaf(p, w, 0.00573950773f);
    p = fmaf(p, w, -0.0076224613f);
    p = fmaf(p, w, 0.00943887047f);
    p = fmaf(p, w, 1.00167406f);
    p = fmaf(p, w, 2.83297682f);
  }
  return p * x;
}

__device__ inline void mdn_head(float yg, float ysg, float ym, int lane, uint32_t rid,
                                uint32_t k1a, uint32_t k1b, uint32_t k2a, uint32_t k2b,
                                float* __restrict__ out) {
  uint32_t pp = rid * (uint32_t)NCdim + (uint32_t)lane;
  uint32_t bits = random_bits32(k1a, k1b, pp);
  float u01 = bits_to_u01(bits);
  const float tinyf = 1.17549435e-38f;
  float uu = fmaxf(tinyf, u01 + tinyf);
  float gum = -logf(-logf(uu));
  float val = gum + yg;
  int idx = lane;
#pragma unroll
  for (int s = 1; s < 64; s <<= 1) {
    float ov = __shfl_xor(val, s);
    int oi = __shfl_xor(idx, s);
    if (ov > val || (ov == val && oi < idx)) { val = ov; idx = oi; }
  }
  float mu_sel = __shfl(ym, idx);
  float s_sel = __shfl(ysg, idx);

  uint32_t ebits = random_bits32(k2a, k2b, rid);
  float ue = bits_to_u01(ebits);
  const float lo = __uint_as_float(0xBF7FFFFFu);
  float un2 = fmaxf(lo, ue * 2.0f + lo);
  float eps = 1.41421356f * erfinv_f32(un2);

  float x_pred = mu_sel + expf(s_sel) * eps;

  float mx = yg;
#pragma unroll
  for (int s = 1; s < 64; s <<= 1) mx = fmaxf(mx, __shfl_xor(mx, s));
  float se = expf(yg - mx);
#pragma unroll
  for (int s = 1; s < 64; s <<= 1) se += __shfl_xor(se, s);
  float d = x_pred - ym;
  float lk = -0.5f * d * d - 66.0f * ysg - 58.812066f;
  float ts = expf(yg - mx + lk);
#pragma unroll
  for (int s = 1; s < 64; s <<= 1) ts += __shfl_xor(ts, s);
  float prob = ts / se;

  if (lane == 0) {
    out[rid] = x_pred;
    out[(size_t)Mdim * Tdim + rid] = prob;
  }
}

// Pack per-ug weight slices (padded rows, gate-interleaved) + FC table. (unchanged)
__global__ void vfpg_prep(const float* __restrict__ Wih0, const float* __restrict__ Whh0,
                          const float* __restrict__ Wih1, const float* __restrict__ Whh1,
                          const float* __restrict__ fcW, const float* __restrict__ bih0,
                          const float* __restrict__ bhh0, const float* __restrict__ bih1,
                          const float* __restrict__ bhh1, float* __restrict__ ws) {
  int i0 = blockIdx.x * blockDim.x + threadIdx.x;
  int n = blockDim.x * gridDim.x;
  const int NWP = NUG * SLICE;
  for (int i = i0; i < NWP; i += n) {
    int ug = i / SLICE, r = i % SLICE;
    float v = 0.0f;
    if (r < 16 * S0P) {
      int gdi = r / S0P, col = r % S0P;
      int gd = (gdi & 3) * 256 + ug * 4 + (gdi >> 2);
      if (col < 16) v = Wih0[gd * INdim + col];
      else if (col < 272) v = Whh0[gd * Hdim + (col - 16)];
    } else if (r < SL_W) {
      int r2 = r - 16 * S0P;
      int gdi = r2 / S1P, col = r2 % S1P;
      int gd = (gdi & 3) * 256 + ug * 4 + (gdi >> 2);
      if (col < 256) v = Wih1[gd * Hdim + col];
      else if (col < 512) v = Whh1[gd * Hdim + (col - 256)];
    } else {
      int r3 = r - SL_W;
      int gdi = (r3 & 15);
      int gd = (gdi & 3) * 256 + ug * 4 + (gdi >> 2);
      v = (r3 < 16) ? (bih0[gd] + bhh0[gd]) : (bih1[gd] + bhh1[gd]);
    }
    ws[OFF_WP + i] = v;
  }
  float4* wfcp = (float4*)(ws + OFF_WFCP);
  for (int o = i0; o < 256 * 64; o += n) {
    int k = o >> 6, c = o & 63;
    wfcp[o] = make_float4(fcW[c * Hdim + k], fcW[(64 + c) * Hdim + k],
                          fcW[(128 + c) * Hdim + k], 0.0f);
  }
}

// In-register lane-pair cell update (R4 pattern). tp=0 holds (i,f), tp=1 holds (g,o).
// Returns c,h for this thread's 4 rows (tp*4+j).
__device__ inline void cell_update(const float aA[8], const float aB[8], int tp,
                                   float4 cold, float4* cnew, float4* hnew) {
  float sa[8], sb[8];
#pragma unroll
  for (int r = 0; r < 8; r++) {
    float xa = tp ? 2.0f * aA[r] : aA[r];
    float s = sigm_fast(xa);
    sa[r] = tp ? fmaf(2.0f, s, -1.0f) : s;
    sb[r] = sigm_fast(aB[r]);
  }
#pragma unroll
  for (int j = 0; j < 4; j++) {
    float s1 = __shfl_xor(tp ? sa[j] : sa[j + 4], 1);
    float s2 = __shfl_xor(tp ? sb[j] : sb[j + 4], 1);
    float own_a = tp ? sa[j + 4] : sa[j];
    float own_b = tp ? sb[j + 4] : sb[j];
    float si = tp ? s1 : own_a;
    float sf = tp ? s2 : own_b;
    float tg = tp ? own_a : s1;
    float so = tp ? own_b : s2;
    float cc = fmaf(sf, (&cold.x)[j], si * tg);
    (&cnew->x)[j] = cc;
    (&hnew->x)[j] = so * fmaf(2.0f, sigm_fast(2.0f * cc), -1.0f);
  }
}

// Launch t: layer0 step t (h0(t)) + layer1 step t-1 (h1(t-1)).
// MODE 0: t=0 (L0 only); 1: 1..63 (both); 2: t=64 (L1 only).
// 256 threads; thread = (r16 = tid>>3: 8-row group, g2 = tid&7 = ul*2+tp).
template <int MODE>
__launch_bounds__(256, 2)
__global__ void vfpg_step(const float* __restrict__ z, const float* __restrict__ ws,
                          float* __restrict__ h0buf, float* __restrict__ c0w,
                          float* __restrict__ c1w, float* __restrict__ ring,
                          float* __restrict__ ring2, int t) {
  constexpr bool DO_L0 = (MODE <= 1);
  constexpr bool DO_L1 = (MODE >= 1);
  __shared__ __align__(16) float lw[SL_W];   // 50.7 KB weights
  __shared__ __align__(16) float lb[32];
  __shared__ __align__(16) float un[4096];   // 16 KB: z-tile / h staging dbuf [2][2048]

  const int tid = threadIdx.x;
  const int rg = blockIdx.x & 7;
  const int ug = blockIdx.x >> 3;
  const int mb = rg * 256;

  {
    const float4* src = (const float4*)(ws + OFF_WP + (size_t)ug * SLICE);
    for (int i = tid; i < SLICE / 4; i += 256) {
      float4 v = src[i];
      if (i < SL_W / 4) ((float4*)lw)[i] = v;
      else ((float4*)lb)[i - SL_W / 4] = v;
    }
  }
  __syncthreads();

  const int r16 = tid >> 3;          // 0..31 (8-row groups)
  const int g2 = tid & 7;            // ul*2+tp
  const int ul = g2 >> 1, tp = g2 & 1;
  const int rA = ul * 4 + 2 * tp;    // slice gate-row A (ty=2tp)
  const int rB = rA + 1;             // slice gate-row B (ty=2tp+1)
  const int u = ug * 4 + ul;
  const int kst = tid >> 6;          // staging k-row base (0..3)
  const int m4 = (tid & 63) * 4;     // staging col

  float a0A[8], a0B[8], a1A[8], a1B[8];
  {
    float bA0 = lb[rA], bB0 = lb[rB], bA1 = lb[16 + rA], bB1 = lb[16 + rB];
#pragma unroll
    for (int r = 0; r < 8; r++) { a0A[r] = bA0; a0B[r] = bB0; a1A[r] = bA1; a1B[r] = bB1; }
  }

  // ---- Z phase (K=16) ----
  if (DO_L0) {
#pragma unroll
    for (int rep = 0; rep < 4; rep++) {
      int it = tid + rep * 256;
      int row = it >> 2, c4 = it & 3;
      *(float4*)&un[row * 16 + c4 * 4] =
          *(const float4*)&z[(size_t)(mb + row) * 1024 + t * 16 + c4 * 4];
    }
    __syncthreads();
#pragma unroll
    for (int f4 = 0; f4 < 4; f4++) {
      float4 wA = *(const float4*)&lw[rA * S0P + f4 * 4];
      float4 wB = *(const float4*)&lw[rB * S0P + f4 * 4];
#pragma unroll
      for (int rr = 0; rr < 8; rr++) {
        float4 q = *(const float4*)&un[(r16 * 8 + rr) * 16 + f4 * 4];
        a0A[rr] = fmaf(q.x, wA.x, a0A[rr]); a0B[rr] = fmaf(q.x, wB.x, a0B[rr]);
        a0A[rr] = fmaf(q.y, wA.y, a0A[rr]); a0B[rr] = fmaf(q.y, wB.y, a0B[rr]);
        a0A[rr] = fmaf(q.z, wA.z, a0A[rr]); a0B[rr] = fmaf(q.z, wB.z, a0B[rr]);
        a0A[rr] = fmaf(q.w, wA.w, a0A[rr]); a0B[rr] = fmaf(q.w, wB.w, a0B[rr]);
      }
    }
    __syncthreads();   // before H0 staging overwrites un
  }

  // ---- H0 phase: h0(t-1), 32 chunks of 8k, dbuf ----
  if (MODE >= 1) {
    const float* h0p = h0buf + (size_t)((t - 1) & 1) * HSLAB + mb;
    float4 s0 = *(const float4*)&h0p[(size_t)kst * 2048 + m4];
    float4 s1 = *(const float4*)&h0p[(size_t)(kst + 4) * 2048 + m4];
#pragma unroll 1
    for (int kk = 0; kk < 32; kk++) {
      float* buf = un + (kk & 1) * 2048;
      *(float4*)&buf[kst * 256 + m4] = s0;
      *(float4*)&buf[(kst + 4) * 256 + m4] = s1;
      if (kk < 31) {
        s0 = *(const float4*)&h0p[(size_t)(kk * 8 + 8 + kst) * 2048 + m4];
        s1 = *(const float4*)&h0p[(size_t)(kk * 8 + 12 + kst) * 2048 + m4];
      }
      __syncthreads();
      float wA0[8], wB0[8], wA1[8], wB1[8];
      if (DO_L0) {
        float4 a = *(const float4*)&lw[rA * S0P + 16 + kk * 8];
        float4 b = *(const float4*)&lw[rA * S0P + 16 + kk * 8 + 4];
        wA0[0]=a.x; wA0[1]=a.y; wA0[2]=a.z; wA0[3]=a.w; wA0[4]=b.x; wA0[5]=b.y; wA0[6]=b.z; wA0[7]=b.w;
        float4 c = *(const float4*)&lw[rB * S0P + 16 + kk * 8];
        float4 d = *(const float4*)&lw[rB * S0P + 16 + kk * 8 + 4];
        wB0[0]=c.x; wB0[1]=c.y; wB0[2]=c.z; wB0[3]=c.w; wB0[4]=d.x; wB0[5]=d.y; wB0[6]=d.z; wB0[7]=d.w;
      }
      if (DO_L1) {
        float4 a = *(const float4*)&lw[W1OFF + rA * S1P + kk * 8];
        float4 b = *(const float4*)&lw[W1OFF + rA * S1P + kk * 8 + 4];
        wA1[0]=a.x; wA1[1]=a.y; wA1[2]=a.z; wA1[3]=a.w; wA1[4]=b.x; wA1[5]=b.y; wA1[6]=b.z; wA1[7]=b.w;
        float4 c = *(const float4*)&lw[W1OFF + rB * S1P + kk * 8];
        float4 d = *(const float4*)&lw[W1OFF + rB * S1P + kk * 8 + 4];
        wB1[0]=c.x; wB1[1]=c.y; wB1[2]=c.z; wB1[3]=c.w; wB1[4]=d.x; wB1[5]=d.y; wB1[6]=d.z; wB1[7]=d.w;
      }
#pragma unroll
      for (int k = 0; k < 8; k++) {
        float4 hA = *(const float4*)&buf[k * 256 + r16 * 8];
        float4 hB = *(const float4*)&buf[k * 256 + r16 * 8 + 4];
        if (DO_L0) {
          a0A[0] = fmaf(hA.x, wA0[k], a0A[0]); a0B[0] = fmaf(hA.x, wB0[k], a0B[0]);
          a0A[1] = fmaf(hA.y, wA0[k], a0A[1]); a0B[1] = fmaf(hA.y, wB0[k], a0B[1]);
          a0A[2] = fmaf(hA.z, wA0[k], a0A[2]); a0B[2] = fmaf(hA.z, wB0[k], a0B[2]);
          a0A[3] = fmaf(hA.w, wA0[k], a0A[3]); a0B[3] = fmaf(hA.w, wB0[k], a0B[3]);
          a0A[4] = fmaf(hB.x, wA0[k], a0A[4]); a0B[4] = fmaf(hB.x, wB0[k], a0B[4]);
          a0A[5] = fmaf(hB.y, wA0[k], a0A[5]); a0B[5] = fmaf(hB.y, wB0[k], a0B[5]);
          a0A[6] = fmaf(hB.z, wA0[k], a0A[6]); a0B[6] = fmaf(hB.z, wB0[k], a0B[6]);
          a0A[7] = fmaf(hB.w, wA0[k], a0A[7]); a0B[7] = fmaf(hB.w, wB0[k], a0B[7]);
        }
        if (DO_L1) {
          a1A[0] = fmaf(hA.x, wA1[k], a1A[0]); a1B[0] = fmaf(hA.x, wB1[k], a1B[0]);
          a1A[1] = fmaf(hA.y, wA1[k], a1A[1]); a1B[1] = fmaf(hA.y, wB1[k], a1B[1]);
          a1A[2] = fmaf(hA.z, wA1[k], a1A[2]); a1B[2] = fmaf(hA.z, wB1[k], a1B[2]);
          a1A[3] = fmaf(hA.w, wA1[k], a1A[3]); a1B[3] = fmaf(hA.w, wB1[k], a1B[3]);
          a1A[4] = fmaf(hB.x, wA1[k], a1A[4]); a1B[4] = fmaf(hB.x, wB1[k], a1B[4]);
          a1A[5] = fmaf(hB.y, wA1[k], a1A[5]); a1B[5] = fmaf(hB.y, wB1[k], a1B[5]);
          a1A[6] = fmaf(hB.z, wA1[k], a1A[6]); a1B[6] = fmaf(hB.z, wB1[k], a1B[6]);
          a1A[7] = fmaf(hB.w, wA1[k], a1A[7]); a1B[7] = fmaf(hB.w, wB1[k], a1B[7]);
        }
      }
    }
  }

  // ---- L0 cell update (in-register, lane-pair) ----
  if (DO_L0) {
    const int mrow = mb + r16 * 8 + tp * 4;
    size_t idx = (size_t)u * 2048 + mrow;
    float4 cold = make_float4(0.f, 0.f, 0.f, 0.f);
    if (MODE == 1) cold = *(const float4*)&c0w[idx];
    float4 cnew, hnew;
    cell_update(a0A, a0B, tp, cold, &cnew, &hnew);
    *(float4*)&c0w[idx] = cnew;
    *(float4*)&(h0buf + (size_t)(t & 1) * HSLAB)[idx] = hnew;
  }

  // ---- H1 phase: h1(t-2), 32 chunks ----
  if (DO_L1 && t >= 2) {
    const float* h1p = ring + (size_t)((t - 2) & 15) * HSLAB + mb;
    float4 s0 = *(const float4*)&h1p[(size_t)kst * 2048 + m4];
    float4 s1 = *(const float4*)&h1p[(size_t)(kst + 4) * 2048 + m4];
    __syncthreads();   // drain H0 compute (or L0 update) before overwriting un
#pragma unroll 1
    for (int kk = 0; kk < 32; kk++) {
      float* buf = un + (kk & 1) * 2048;
      *(float4*)&buf[kst * 256 + m4] = s0;
      *(float4*)&buf[(kst + 4) * 256 + m4] = s1;
      if (kk < 31) {
        s0 = *(const float4*)&h1p[(size_t)(kk * 8 + 8 + kst) * 2048 + m4];
        s1 = *(const float4*)&h1p[(size_t)(kk * 8 + 12 + kst) * 2048 + m4];
      }
      __syncthreads();
      float4 a = *(const float4*)&lw[W1OFF + rA * S1P + 256 + kk * 8];
      float4 b = *(const float4*)&lw[W1OFF + rA * S1P + 256 + kk * 8 + 4];
      float4 c = *(const float4*)&lw[W1OFF + rB * S1P + 256 + kk * 8];
      float4 d = *(const float4*)&lw[W1OFF + rB * S1P + 256 + kk * 8 + 4];
      float wA1[8] = {a.x, a.y, a.z, a.w, b.x, b.y, b.z, b.w};
      float wB1[8] = {c.x, c.y, c.z, c.w, d.x, d.y, d.z, d.w};
#pragma unroll
      for (int k = 0; k < 8; k++) {
        float4 hA = *(const float4*)&buf[k * 256 + r16 * 8];
        float4 hB = *(const float4*)&buf[k * 256 + r16 * 8 + 4];
        a1A[0] = fmaf(hA.x, wA1[k], a1A[0]); a1B[0] = fmaf(hA.x, wB1[k], a1B[0]);
        a1A[1] = fmaf(hA.y, wA1[k], a1A[1]); a1B[1] = fmaf(hA.y, wB1[k], a1B[1]);
        a1A[2] = fmaf(hA.z, wA1[k], a1A[2]); a1B[2] = fmaf(hA.z, wB1[k], a1B[2]);
        a1A[3] = fmaf(hA.w, wA1[k], a1A[3]); a1B[3] = fmaf(hA.w, wB1[k], a1B[3]);
        a1A[4] = fmaf(hB.x, wA1[k], a1A[4]); a1B[4] = fmaf(hB.x, wB1[k], a1B[4]);
        a1A[5] = fmaf(hB.y, wA1[k], a1A[5]); a1B[5] = fmaf(hB.y, wB1[k], a1B[5]);
        a1A[6] = fmaf(hB.z, wA1[k], a1A[6]); a1B[6] = fmaf(hB.z, wB1[k], a1B[6]);
        a1A[7] = fmaf(hB.w, wA1[k], a1A[7]); a1B[7] = fmaf(hB.w, wB1[k], a1B[7]);
      }
    }
  }

  // ---- L1 cell update (h1(t-1)) ----
  if (DO_L1) {
    const int mrow = mb + r16 * 8 + tp * 4;
    size_t idx = (size_t)u * 2048 + mrow;
    float4 cold = make_float4(0.f, 0.f, 0.f, 0.f);
    if (MODE == 2 || t >= 2) cold = *(const float4*)&c1w[idx];
    float4 cnew, hnew;
    cell_update(a1A, a1B, tp, cold, &cnew, &hnew);
    *(float4*)&c1w[idx] = cnew;
    int slot = (t - 1) & 15;
    *(float4*)&(ring + (size_t)slot * HSLAB)[idx] = hnew;
    float* r2 = ring2 + (size_t)slot * HSLAB;
#pragma unroll
    for (int j = 0; j < 4; j++) r2[(size_t)(mrow + j) * 256 + u] = (&hnew.x)[j];
  }
}

// Head: FC + MDN for 16 slots x 2048 rows; wave = 8 rows (w-loads shared).
__launch_bounds__(512, 2)
__global__ void vfpg_head(const float* __restrict__ ws, const float* __restrict__ fcb,
                          float* __restrict__ out, int tbase,
                          uint32_t k1a, uint32_t k1b, uint32_t k2a, uint32_t k2b) {
  __shared__ __align__(16) float hsw[8][8][Hdim];   // 64 KB
  const int tid = threadIdx.x;
  const int lane = tid & 63, wid = tid >> 6;
  const int rb8 = blockIdx.x * 8 + wid;      // 0..4095 (8-row groups)
  const int slot = rb8 >> 8;                 // 0..15
  const int mbase = (rb8 & 255) * 8;

  const float* r2 = ws + OFF_RING2 + (size_t)slot * HSLAB + (size_t)mbase * 256;
  const float4* WFCP = (const float4*)(ws + OFF_WFCP);

#pragma unroll
  for (int rr = 0; rr < 8; rr++)
    *(float4*)&hsw[wid][rr][lane * 4] = *(const float4*)&r2[rr * 256 + lane * 4];
  __builtin_amdgcn_s_waitcnt(0);

  float yg[8], ys[8], ym[8];
#pragma unroll
  for (int rr = 0; rr < 8; rr++) {
    yg[rr] = fcb[lane]; ys[rr] = fcb[64 + lane]; ym[rr] = fcb[128 + lane];
  }
#pragma unroll 2
  for (int k4 = 0; k4 < 64; k4++) {
#pragma unroll
    for (int j = 0; j < 4; j++) {
      float4 w = WFCP[(k4 * 4 + j) * 64 + lane];
#pragma unroll
      for (int rr = 0; rr < 8; rr++) {
        float hv = hsw[wid][rr][k4 * 4 + j];
        yg[rr] = fmaf(hv, w.x, yg[rr]);
        ys[rr] = fmaf(hv, w.y, ys[rr]);
        ym[rr] = fmaf(hv, w.z, ym[rr]);
      }
    }
  }
  int tt = tbase + slot;
#pragma unroll 1
  for (int rr = 0; rr < 8; rr++) {
    uint32_t rid = (uint32_t)(mbase + rr) * Tdim + (uint32_t)tt;
    mdn_head(yg[rr], ys[rr], ym[rr], lane, rid, k1a, k1b, k2a, k2b, out);
  }
}

extern "C" void kernel_launch(void* const* d_in, const int* in_sizes, int n_in,
                              void* d_out, int out_size, void* d_ws, size_t ws_size,
                              hipStream_t stream) {
  const float* z    = (const float*)d_in[0];
  const float* Wih0 = (const float*)d_in[1];
  const float* Whh0 = (const float*)d_in[2];
  const float* bih0 = (const float*)d_in[3];
  const float* bhh0 = (const float*)d_in[4];
  const float* Wih1 = (const float*)d_in[5];
  const float* Whh1 = (const float*)d_in[6];
  const float* bih1 = (const float*)d_in[7];
  const float* bhh1 = (const float*)d_in[8];
  const float* fcW  = (const float*)d_in[9];
  const float* fcb  = (const float*)d_in[10];
  float* ws = (float*)d_ws;
  float* out = (float*)d_out;

  if (ws_size < (size_t)WS_TOT * sizeof(float)) return;

  vfpg_prep<<<dim3(512), dim3(256), 0, stream>>>(
      Wih0, Whh0, Wih1, Whh1, fcW, bih0, bhh0, bih1, bhh1, ws);

  uint32_t k1a, k1b, k2a, k2b;
  tf2x32(0u, 42u, 0u, 0u, &k1a, &k1b);
  tf2x32(0u, 42u, 0u, 1u, &k2a, &k2b);

  float* h0buf = ws + OFF_H0;
  float* c0w = ws + OFF_C0;
  float* c1w = ws + OFF_C1;
  float* ring = ws + OFF_RING;
  float* ring2 = ws + OFF_RING2;

  vfpg_step<0><<<dim3(512), dim3(256), 0, stream>>>(z, ws, h0buf, c0w, c1w, ring, ring2, 0);
  for (int t = 1; t <= 63; t++) {
    vfpg_step<1><<<dim3(512), dim3(256), 0, stream>>>(z, ws, h0buf, c0w, c1w, ring, ring2, t);
    if (t == 16 || t == 32 || t == 48) {
      vfpg_head<<<dim3(512), dim3(512), 0, stream>>>(ws, fcb, out, t - 16,
                                                     k1a, k1b, k2a, k2b);
    }
  }
  vfpg_step<2><<<dim3(512), dim3(256), 0, stream>>>(z, ws, h0buf, c0w, c1w, ring, ring2, 64);
  vfpg_head<<<dim3(512), dim3(512), 0, stream>>>(ws, fcb, out, 48, k1a, k1b, k2a, k2b);
}